// Round 5
// baseline (357.979 us; speedup 1.0000x reference)
//
#include <hip/hip_runtime.h>

#define TT 4096
#define BLK 256
#define PER 16     // TT / BLK
#define TPB 4      // traces per block; grid = 8192/4 = 2048 = 8 blocks/CU, persistent
#define EPSV 1e-8f

// Async global->LDS, 16 B per lane. LDS dest = wave-uniform base + lane*16.
__device__ __forceinline__ void async_q16(const float* g, float* l) {
  __builtin_amdgcn_global_load_lds(
      (const __attribute__((address_space(1))) void*)g,
      (__attribute__((address_space(3))) void*)l, 16, 0, 0);
}

// Compile-time float4 component select (folds after full unroll).
__device__ __forceinline__ float fcomp(const float4& v, int c) {
  switch (c) {
    case 0: return v.x;
    case 1: return v.y;
    case 2: return v.z;
    default: return v.w;
  }
}

__global__ __launch_bounds__(BLK, 8) void w2_loss_kernel(
    const float* __restrict__ traces,
    const float* __restrict__ q_raw,
    float* __restrict__ part) {
  __shared__ float qb[TT];        // single q stage (16 KB) -> 8 blocks/CU
  __shared__ float wave_sums[4];
  __shared__ float wave_red[4];

  const int tid = threadIdx.x;
  const int wv = tid >> 6;
  const int lane = tid & 63;
  const long trace0 = (long)blockIdx.x * TPB;
  const int base = tid * PER;

  // ---- Prologue: trace-0 regs FIRST (older vmem -> their waits leave the
  // q glds in flight), then q-0 async staging. ----
  float4 trv[2][4];
  float nbuf[2];
  {
    const float* tr = traces + trace0 * (long)TT;
    const float4* tr4 = (const float4*)(tr + base);
#pragma unroll
    for (int j = 0; j < 4; ++j) trv[0][j] = tr4[j];
    nbuf[0] = (tid < BLK - 1) ? tr[base + PER] : 0.0f;
    const float* qr = q_raw + trace0 * (long)TT;
#pragma unroll
    for (int j = 0; j < 4; ++j) {
      const int c = (wv * 4 + j) * 256;          // wave-uniform chunk base
      async_q16(qr + c + lane * 4, &qb[c]);
    }
  }

#pragma unroll
  for (int k = 0; k < TPB; ++k) {
    const int cur = k & 1, nxt = cur ^ 1;        // compile-time after unroll
    const long trace = trace0 + k;

    // ---- Phase 1: squares IN PLACE (trv[cur] becomes s0..s15) ----
#pragma unroll
    for (int j = 0; j < 4; ++j) {
      trv[cur][j].x = trv[cur][j].x * trv[cur][j].x + EPSV;
      trv[cur][j].y = trv[cur][j].y * trv[cur][j].y + EPSV;
      trv[cur][j].z = trv[cur][j].z * trv[cur][j].z + EPSV;
      trv[cur][j].w = trv[cur][j].w * trv[cur][j].w + EPSV;
    }
    const float s16 = (tid < BLK - 1) ? (nbuf[cur] * nbuf[cur] + EPSV) : 0.0f;

    // Thread total of trapz increments (rolling t; same float values/order
    // as the original lc build — only the prefix array is not kept).
    float tot = 0.0f;
    {
      float t0 = (float)base * 1e-3f;
#pragma unroll
      for (int m = 0; m < PER; ++m) {
        float t1 = (float)(base + m + 1) * 1e-3f;
        float sm = fcomp(trv[cur][m >> 2], m & 3);
        float sm1 = (m < PER - 1) ? fcomp(trv[cur][(m + 1) >> 2], (m + 1) & 3) : s16;
        float incr = 0.5f * (sm + sm1) * (t1 - t0);
        if (m == PER - 1) incr = (tid < BLK - 1) ? incr : 0.0f;  // only tail can differ
        tot = tot + incr;
        t0 = t1;
      }
    }

    // Wave-level inclusive scan of thread totals (wave = 64 lanes).
    float v = tot;
#pragma unroll
    for (int off = 1; off < 64; off <<= 1) {
      float n = __shfl_up(v, off, 64);
      if (lane >= off) v += n;
    }
    if (lane == 63) wave_sums[wv] = v;
    __syncthreads();  // B1: wave_sums visible; q glds for trace k landed

    float wave_off = 0.0f;
    if (wv > 0) wave_off += wave_sums[0];
    if (wv > 1) wave_off += wave_sums[1];
    if (wv > 2) wave_off += wave_sums[2];
    const float excl = (v - tot) + wave_off;
    const float norm = wave_sums[0] + wave_sums[1] + wave_sums[2] + wave_sums[3];
    const float inv_norm = 1.0f / norm;

    // Prefetch next trace into the other register buffer (covered by phase 2).
    if (k + 1 < TPB) {
      const float* trn = traces + (trace + 1) * (long)TT;
      const float4* tr4n = (const float4*)(trn + base);
#pragma unroll
      for (int j = 0; j < 4; ++j) trv[nxt][j] = tr4n[j];
      nbuf[nxt] = (tid < BLK - 1) ? trn[base + PER] : 0.0f;
    }

    // ---- Phase 2: cdf -> analytic-p interp -> loss. Prefix recomputed
    // incrementally (identical adds/order as the original lc[]). ----
    float local = 0.0f;
    {
      float tlo = (tid == 0) ? 0.0f : (float)(base - 1) * 1e-3f;
      float tm = (float)base * 1e-3f;
      float lcm = 0.0f;  // == lc[m] at loop top
#pragma unroll
      for (int m = 0; m < PER; ++m) {
        float thi = (float)(base + m + 1) * 1e-3f;
        float thi_w = thi;
        if (m == PER - 1) thi_w = (tid == BLK - 1) ? tm : thi;  // t[4095] edge
        float x = (excl + lcm) * inv_norm;       // cdf in [0,1]
        float u = x * (float)(TT - 1);           // u >= 0 always (s > 0)
        int i0 = (int)u;                         // == floorf for u >= 0
        i0 = (i0 > TT - 2) ? TT - 2 : i0;
        float f = u - (float)i0;                 // >= 0 by construction
        f = fminf(f, 1.0f);                      // jnp.interp endpoint clamp
        float q0 = qb[i0];
        float q1 = qb[i0 + 1];
        float transport = q0 + f * (q1 - q0);
        float d = tm - transport;
        float w = 0.5f * (thi_w - tlo);          // collapsed trapz weight
        local += d * d * fcomp(trv[cur][m >> 2], m & 3) * w;
        if (m < PER - 1) {                       // advance prefix (same floats)
          float sm = fcomp(trv[cur][m >> 2], m & 3);
          float sm1 = fcomp(trv[cur][(m + 1) >> 2], (m + 1) & 3);
          lcm = lcm + 0.5f * (sm + sm1) * (thi - tm);
        }
        tlo = tm;
        tm = thi;
      }
    }
    local *= inv_norm;

    // ---- Block reduce, one coalesced store per trace ----
#pragma unroll
    for (int off = 32; off > 0; off >>= 1) local += __shfl_down(local, off, 64);
    if (lane == 0) wave_red[wv] = local;
    __syncthreads();  // B2: wave_red visible; all qb reads done; trv[nxt] drained
    if (tid == 0) {
      part[trace] = wave_red[0] + wave_red[1] + wave_red[2] + wave_red[3];
    }
    // Issue next q staging AFTER B2 (qb free); lands before B1(k+1) drain,
    // partially covered by the store + phase-1 of the next trace.
    if (k + 1 < TPB) {
      const float* qrn = q_raw + (trace + 1) * (long)TT;
#pragma unroll
      for (int j = 0; j < 4; ++j) {
        const int c = (wv * 4 + j) * 256;
        async_q16(qrn + c + lane * 4, &qb[c]);
      }
    }
    // wave_sums(k+1) written after B2(k); wave_red(k+1) written after B1(k+1);
    // tid0 reads wave_red before B1(k+1) -> race-free.
  }
}

__global__ __launch_bounds__(BLK) void reduce_kernel(
    const float* __restrict__ part, float* __restrict__ out, int n) {
  __shared__ float wave_red[4];
  const int tid = threadIdx.x;
  float local = 0.0f;
  for (int i = tid; i < n; i += BLK) local += part[i];
#pragma unroll
  for (int off = 32; off > 0; off >>= 1) local += __shfl_down(local, off, 64);
  if ((tid & 63) == 0) wave_red[tid >> 6] = local;
  __syncthreads();
  if (tid == 0) out[0] = wave_red[0] + wave_red[1] + wave_red[2] + wave_red[3];
}

extern "C" void kernel_launch(void* const* d_in, const int* in_sizes, int n_in,
                              void* d_out, int out_size, void* d_ws, size_t ws_size,
                              hipStream_t stream) {
  const float* traces = (const float*)d_in[0];
  const float* q_raw  = (const float*)d_in[3];
  float* out = (float*)d_out;
  float* part = (float*)d_ws;  // 8192 floats = 32 KB scratch

  const int n_traces = in_sizes[0] / TT;   // B*R = 8192
  const int n_blocks = n_traces / TPB;     // 2048 = 8 blocks/CU, persistent
  w2_loss_kernel<<<n_blocks, BLK, 0, stream>>>(traces, q_raw, part);
  reduce_kernel<<<1, BLK, 0, stream>>>(part, out, n_traces);
}

// Round 6
// 283.828 us; speedup vs baseline: 1.2613x; 1.2613x over previous
//
#include <hip/hip_runtime.h>

#define TT 4096
#define BLK 256
#define PER 16   // TT / BLK
#define EPSV 1e-8f

// Async global->LDS, 16 B per lane. LDS dest = wave-uniform base + lane*16.
__device__ __forceinline__ void async_q16(const float* g, float* l) {
  __builtin_amdgcn_global_load_lds(
      (const __attribute__((address_space(1))) void*)g,
      (__attribute__((address_space(3))) void*)l, 16, 0, 0);
}

__global__ __launch_bounds__(BLK) void w2_loss_kernel(
    const float* __restrict__ traces,
    const float* __restrict__ q_raw,
    float* __restrict__ part) {
  __shared__ float qb[TT];        // q stage (16 KB) — same LDS footprint as R0
  __shared__ float wave_sums[4];
  __shared__ float wave_red[4];

  const int tid = threadIdx.x;
  const int wv = tid >> 6;
  const int lane = tid & 63;
  const long trace = blockIdx.x;
  const float* __restrict__ tr = traces + trace * (long)TT;
  const float* __restrict__ qr = q_raw + trace * (long)TT;
  const int base = tid * PER;

  // ---- trace loads FIRST (older vmem -> scan's wait leaves glds in flight) ----
  float4 trv[4];
  {
    const float4* tr4 = (const float4*)(tr + base);
#pragma unroll
    for (int j = 0; j < 4; ++j) trv[j] = tr4[j];
  }
  float nb = (tid < BLK - 1) ? tr[base + PER] : 0.0f;

  // ---- q staging via async global->LDS: no VGPR round-trip, no ds_writes.
  // The __syncthreads below (vmcnt(0) drain) guarantees landing. ----
#pragma unroll
  for (int j = 0; j < 4; ++j) {
    const int c = (wv * 4 + j) * 256;            // wave-uniform chunk base
    async_q16(qr + c + lane * 4, &qb[c]);
  }

  // s[i] = traces[i]^2 + eps for own 16 elements + right neighbor (as R0).
  float s[PER + 1];
#pragma unroll
  for (int j = 0; j < 4; ++j) {
    s[4 * j + 0] = trv[j].x * trv[j].x + EPSV;
    s[4 * j + 1] = trv[j].y * trv[j].y + EPSV;
    s[4 * j + 2] = trv[j].z * trv[j].z + EPSV;
    s[4 * j + 3] = trv[j].w * trv[j].w + EPSV;
  }
  s[PER] = (tid < BLK - 1) ? (nb * nb + EPSV) : 0.0f;

  // Per-thread cumtrapz prefix. Rolling t: each (float)(i)*1e-3f computed
  // once — identical float values/order as R0's per-m t0/t1 build.
  float lc[PER + 1];
  lc[0] = 0.0f;
  {
    float t0 = (float)base * 1e-3f;
#pragma unroll
    for (int m = 0; m < PER; ++m) {
      float t1 = (float)(base + m + 1) * 1e-3f;
      float incr = 0.5f * (s[m] + s[m + 1]) * (t1 - t0);
      if (m == PER - 1) incr = (tid < BLK - 1) ? incr : 0.0f;  // only possible edge
      lc[m + 1] = lc[m] + incr;
      t0 = t1;
    }
  }
  const float tot = lc[PER];

  // Wave-level inclusive scan of thread totals (wave = 64 lanes) — as R0.
  float v = tot;
#pragma unroll
  for (int off = 1; off < 64; off <<= 1) {
    float n = __shfl_up(v, off, 64);
    if (lane >= off) v += n;
  }
  if (lane == 63) wave_sums[wv] = v;
  __syncthreads();  // covers wave_sums AND the async q staging (vmcnt drain)

  float wave_off = 0.0f;
  if (wv > 0) wave_off += wave_sums[0];
  if (wv > 1) wave_off += wave_sums[1];
  if (wv > 2) wave_off += wave_sums[2];
  const float excl = (v - tot) + wave_off;
  const float norm = wave_sums[0] + wave_sums[1] + wave_sums[2] + wave_sums[3];
  const float inv_norm = 1.0f / norm;

  // ---- Phase 2: cdf -> analytic-p interp -> loss. VALU diet, bit-exact:
  // rolling tm/tlo/thi; floorf -> int cast (u >= 0 provable: all scan
  // summands nonnegative => v >= tot => excl >= 0); i0 lower clamp and
  // fmax(f,0) provably dead; upper clamp + fminf(f,1) kept (jnp.interp). ----
  float local = 0.0f;
  {
    float tlo = (tid == 0) ? 0.0f : (float)(base - 1) * 1e-3f;
    float tm = (float)base * 1e-3f;
#pragma unroll
    for (int m = 0; m < PER; ++m) {
      float thi = (float)(base + m + 1) * 1e-3f;
      float thi_w = thi;
      if (m == PER - 1) thi_w = (tid == BLK - 1) ? tm : thi;  // t[4095] edge
      float x = (excl + lc[m]) * inv_norm;       // cdf in [0,1]
      float u = x * (float)(TT - 1);             // analytic index on uniform p
      int i0 = (int)u;                           // == floorf for u >= 0
      i0 = (i0 > TT - 2) ? TT - 2 : i0;
      float f = u - (float)i0;                   // >= 0 by construction
      f = fminf(f, 1.0f);                        // jnp.interp endpoint clamp
      float q0 = qb[i0];
      float q1 = qb[i0 + 1];
      float transport = q0 + f * (q1 - q0);
      float d = tm - transport;
      float w = 0.5f * (thi_w - tlo);            // collapsed trapz weight
      local += d * d * s[m] * w;                 // ((d*d)*s[m])*w — as R0
      tlo = tm;
      tm = thi;
    }
  }
  local *= inv_norm;

  // Block reduce, then ONE coalesced store per block — as R0.
#pragma unroll
  for (int off = 32; off > 0; off >>= 1) local += __shfl_down(local, off, 64);
  if (lane == 0) wave_red[wv] = local;
  __syncthreads();
  if (tid == 0) {
    part[blockIdx.x] = wave_red[0] + wave_red[1] + wave_red[2] + wave_red[3];
  }
}

__global__ __launch_bounds__(BLK) void reduce_kernel(
    const float* __restrict__ part, float* __restrict__ out, int n) {
  __shared__ float wave_red[4];
  const int tid = threadIdx.x;
  float local = 0.0f;
  for (int i = tid; i < n; i += BLK) local += part[i];
#pragma unroll
  for (int off = 32; off > 0; off >>= 1) local += __shfl_down(local, off, 64);
  if ((tid & 63) == 0) wave_red[tid >> 6] = local;
  __syncthreads();
  if (tid == 0) out[0] = wave_red[0] + wave_red[1] + wave_red[2] + wave_red[3];
}

extern "C" void kernel_launch(void* const* d_in, const int* in_sizes, int n_in,
                              void* d_out, int out_size, void* d_ws, size_t ws_size,
                              hipStream_t stream) {
  const float* traces = (const float*)d_in[0];
  const float* q_raw  = (const float*)d_in[3];
  float* out = (float*)d_out;
  float* part = (float*)d_ws;  // 8192 floats = 32 KB scratch

  const int n_traces = in_sizes[0] / TT;  // B*R = 8192
  w2_loss_kernel<<<n_traces, BLK, 0, stream>>>(traces, q_raw, part);
  reduce_kernel<<<1, BLK, 0, stream>>>(part, out, n_traces);
}

// Round 7
// 282.662 us; speedup vs baseline: 1.2665x; 1.0041x over previous
//
#include <hip/hip_runtime.h>

#define TT 4096
#define BLK 256
#define PER 16   // TT / BLK
#define EPSV 1e-8f

// Async global->LDS, 16 B per lane. LDS dest = wave-uniform base + lane*16.
__device__ __forceinline__ void async_q16(const float* g, float* l) {
  __builtin_amdgcn_global_load_lds(
      (const __attribute__((address_space(1))) void*)g,
      (__attribute__((address_space(3))) void*)l, 16, 0, 0);
}

__global__ __launch_bounds__(BLK) void w2_loss_kernel(
    const float* __restrict__ traces,
    const float* __restrict__ q_raw,
    float* __restrict__ part) {
  __shared__ float qb[TT];        // q stage (16 KB)
  __shared__ float wave_sums[4];
  __shared__ float wave_red[4];

  const int tid = threadIdx.x;
  const int wv = tid >> 6;
  const int lane = tid & 63;
  const long trace = blockIdx.x;
  const float* __restrict__ tr = traces + trace * (long)TT;
  const float* __restrict__ qr = q_raw + trace * (long)TT;
  const int base = tid * PER;

  // ---- trace loads FIRST (older in vmcnt queue than the glds below, so the
  // scan's wait for them leaves the q staging in flight) ----
  float4 trv[4];
  {
    const float4* tr4 = (const float4*)(tr + base);
#pragma unroll
    for (int j = 0; j < 4; ++j) trv[j] = tr4[j];
  }
  float nb = (tid < BLK - 1) ? tr[base + PER] : 0.0f;

  // ---- q staging via async global->LDS (landing guaranteed by the
  // vmcnt(0) drain at the __syncthreads below) ----
#pragma unroll
  for (int j = 0; j < 4; ++j) {
    const int c = (wv * 4 + j) * 256;            // wave-uniform chunk base
    async_q16(qr + c + lane * 4, &qb[c]);
  }

  // s[i] = traces[i]^2 + eps for own 16 elements + right neighbor (as R0).
  float s[PER + 1];
#pragma unroll
  for (int j = 0; j < 4; ++j) {
    s[4 * j + 0] = trv[j].x * trv[j].x + EPSV;
    s[4 * j + 1] = trv[j].y * trv[j].y + EPSV;
    s[4 * j + 2] = trv[j].z * trv[j].z + EPSV;
    s[4 * j + 3] = trv[j].w * trv[j].w + EPSV;
  }
  s[PER] = (tid < BLK - 1) ? (nb * nb + EPSV) : 0.0f;

  // Per-thread cumtrapz prefix (rolling t; identical float ops as R0).
  float lc[PER + 1];
  lc[0] = 0.0f;
  {
    float t0 = (float)base * 1e-3f;
#pragma unroll
    for (int m = 0; m < PER; ++m) {
      float t1 = (float)(base + m + 1) * 1e-3f;
      float incr = 0.5f * (s[m] + s[m + 1]) * (t1 - t0);
      if (m == PER - 1) incr = (tid < BLK - 1) ? incr : 0.0f;
      lc[m + 1] = lc[m] + incr;
      t0 = t1;
    }
  }
  const float tot = lc[PER];

  // Wave-level inclusive scan of thread totals (wave = 64 lanes) — as R0.
  float v = tot;
#pragma unroll
  for (int off = 1; off < 64; off <<= 1) {
    float n = __shfl_up(v, off, 64);
    if (lane >= off) v += n;
  }
  if (lane == 63) wave_sums[wv] = v;
  __syncthreads();  // covers wave_sums AND the async q staging (vmcnt drain)

  float wave_off = 0.0f;
  if (wv > 0) wave_off += wave_sums[0];
  if (wv > 1) wave_off += wave_sums[1];
  if (wv > 2) wave_off += wave_sums[2];
  const float excl = (v - tot) + wave_off;
  const float norm = wave_sums[0] + wave_sums[1] + wave_sums[2] + wave_sums[3];
  const float inv_norm = 1.0f / norm;

  // ---- Phase 2, BATCHED for memory-level parallelism: per group of 8,
  // compute all addresses, issue all 16 LDS reads into registers, then
  // consume in original m-order. Arithmetic/accumulation order verbatim R6
  // (bit-exact). All array indices are compile-time after full unroll. ----
  float local = 0.0f;
  {
    float tlo = (tid == 0) ? 0.0f : (float)(base - 1) * 1e-3f;
    float tm = (float)base * 1e-3f;
#pragma unroll
    for (int g = 0; g < 2; ++g) {
      int idx[8];
      float ff[8];
#pragma unroll
      for (int mm = 0; mm < 8; ++mm) {
        const int m = 8 * g + mm;
        float x = (excl + lc[m]) * inv_norm;     // cdf in [0,1]
        float u = x * (float)(TT - 1);           // u >= 0 (all summands >= 0)
        int i0 = (int)u;                         // == floorf for u >= 0
        i0 = (i0 > TT - 2) ? TT - 2 : i0;
        float f = u - (float)i0;                 // >= 0 by construction
        idx[mm] = i0;
        ff[mm] = fminf(f, 1.0f);                 // jnp.interp endpoint clamp
      }
      float q0v[8], q1v[8];
#pragma unroll
      for (int mm = 0; mm < 8; ++mm) {
        q0v[mm] = qb[idx[mm]];                   // 16 independent ds_reads:
        q1v[mm] = qb[idx[mm] + 1];               // issue together, wait once
      }
#pragma unroll
      for (int mm = 0; mm < 8; ++mm) {
        const int m = 8 * g + mm;
        float thi = (float)(base + m + 1) * 1e-3f;
        float thi_w = thi;
        if (m == PER - 1) thi_w = (tid == BLK - 1) ? tm : thi;  // t[4095] edge
        float transport = q0v[mm] + ff[mm] * (q1v[mm] - q0v[mm]);
        float d = tm - transport;
        float w = 0.5f * (thi_w - tlo);          // collapsed trapz weight
        local += d * d * s[m] * w;               // ((d*d)*s[m])*w — as R0
        tlo = tm;
        tm = thi;
      }
    }
  }
  local *= inv_norm;

  // Block reduce, then ONE coalesced store per block — as R0.
#pragma unroll
  for (int off = 32; off > 0; off >>= 1) local += __shfl_down(local, off, 64);
  if (lane == 0) wave_red[wv] = local;
  __syncthreads();
  if (tid == 0) {
    part[blockIdx.x] = wave_red[0] + wave_red[1] + wave_red[2] + wave_red[3];
  }
}

__global__ __launch_bounds__(BLK) void reduce_kernel(
    const float* __restrict__ part, float* __restrict__ out, int n) {
  __shared__ float wave_red[4];
  const int tid = threadIdx.x;
  float local = 0.0f;
  for (int i = tid; i < n; i += BLK) local += part[i];
#pragma unroll
  for (int off = 32; off > 0; off >>= 1) local += __shfl_down(local, off, 64);
  if ((tid & 63) == 0) wave_red[tid >> 6] = local;
  __syncthreads();
  if (tid == 0) out[0] = wave_red[0] + wave_red[1] + wave_red[2] + wave_red[3];
}

extern "C" void kernel_launch(void* const* d_in, const int* in_sizes, int n_in,
                              void* d_out, int out_size, void* d_ws, size_t ws_size,
                              hipStream_t stream) {
  const float* traces = (const float*)d_in[0];
  const float* q_raw  = (const float*)d_in[3];
  float* out = (float*)d_out;
  float* part = (float*)d_ws;  // 8192 floats = 32 KB scratch

  const int n_traces = in_sizes[0] / TT;  // B*R = 8192
  w2_loss_kernel<<<n_traces, BLK, 0, stream>>>(traces, q_raw, part);
  reduce_kernel<<<1, BLK, 0, stream>>>(part, out, n_traces);
}